// Round 11
// baseline (402.708 us; speedup 1.0000x reference)
//
#include <hip/hip_runtime.h>
#include <math.h>

#define BATCH 32
#define SEQ   4096
#define DM    256
#define NS    64
#define TSTEP 32   // time steps per staged LDS tile (2 float4 loads per lane)

// z-space recurrence: z = a*z + u, x = B_tilde * z exactly.
// y = sum_n (C*B_tilde)[n] * z[n].
// chain = one (b,d) recurrence. 4 lanes per chain, 16 states per lane.
// wave = 64 lanes = 16 chains = (one b, 16 consecutive d).
// Round-11 structure (r7 + two fixes):
//  - TSTEP=32: tile compute span 1184cyc > ~900cyc HBM latency. r10 showed
//    pass1 (16 FMA/step, 592cyc span) ran as slow as pass3: latency-bound.
//  - passA = pass1 (chunks 0..C-2) + chunk-0 emit fused in one launch.
//    Chunk 0 needs no carry (z_in = x0); its 128 emit blocks are dispatched
//    FIRST (blockIdx < 128) and finish inside pass1's bulk. pass3 then only
//    emits chunks 1..C-1.
//  - pass2 restored verbatim (r10's folded lookback cost +23us in L2/L3
//    burst; the shared prefix kernel does it for ~15us off-path).

// ---------------- passA: chunk-0 emit (blocks 0..127) + pass1 ----------------
__global__ __launch_bounds__(256, 2)
void passA_kernel(const float* __restrict__ u,
                  const float* __restrict__ log_dt,
                  const float* __restrict__ A_real,
                  const float* __restrict__ B,
                  const float* __restrict__ Cm,
                  float* __restrict__ S,
                  const float* __restrict__ x0,
                  float* __restrict__ y, int Tc) {
    __shared__ float tiles[4][2][TSTEP][16];  // 16 KB
    int wid  = threadIdx.x >> 6;
    int lane = threadIdx.x & 63;
    bool emit = (blockIdx.x < 128);
    int wave, g;
    if (emit) { wave = (blockIdx.x << 2) | wid;         g = 0; }
    else      { wave = ((blockIdx.x - 128) << 2) | wid; g = wave >> 9; }
    int w  = wave & 511;
    int b  = w >> 4;
    int d0 = (w & 15) << 4;
    int c   = lane >> 2;   // chain within wave (0..15)
    int sub = lane & 3;    // quarter of the state vector
    int d   = d0 + c;
    int n0  = sub << 4;

    float dt = expf(log_dt[d]);  // DT_SCALE = 1.0
    const float* Ap = A_real + d * NS + n0;
    float a[16], z[16];
#pragma unroll
    for (int k = 0; k < 16; ++k)
        a[k] = expf(Ap[k] * dt);

    const size_t tadv = (size_t)TSTEP * DM;
    const size_t half = (size_t)16 * DM;
    float* slotA = &tiles[wid][0][0][0] + (lane << 2);  // lane's 16B, rows 0-15
    const int ntiles = Tc / TSTEP;                      // >= 8 for all C
    const float* gsrc = u + (size_t)b * SEQ * DM + (size_t)(g * Tc) * DM
                        + (size_t)(lane >> 2) * DM + d0 + ((lane & 3) << 2);

    if (!emit) {
        // ---- pass1 role: local z-scan from zero, publish end state E_g ----
#pragma unroll
        for (int k = 0; k < 16; ++k) z[k] = 0.0f;
        float4 rC = *(const float4*)gsrc;
        float4 rD = *(const float4*)(gsrc + half);
        *(float4*)slotA = rC;
        *(float4*)(slotA + 256) = rD;
        rC = *(const float4*)(gsrc + tadv);
        rD = *(const float4*)(gsrc + tadv + half);
        gsrc += 2 * tadv;
        for (int t = 0; t < ntiles; ++t) {
            if (t + 1 < ntiles) {
                float* wp = slotA + (((t + 1) & 1) << 9);
                *(float4*)wp = rC;
                *(float4*)(wp + 256) = rD;
            }
            if (t + 2 < ntiles) {
                rC = *(const float4*)gsrc;
                rD = *(const float4*)(gsrc + half);
                gsrc += tadv;
            }
            const float* tb = &tiles[wid][t & 1][0][0] + c;
#pragma unroll
            for (int s = 0; s < TSTEP; ++s) {
                float uv = tb[s << 4];          // broadcast ds_read_b32
#pragma unroll
                for (int k = 0; k < 16; ++k)
                    z[k] = fmaf(a[k], z[k], uv);
            }
        }
        float* Sp = S + (((size_t)g * BATCH + b) * DM + d) * NS + n0;
        float4* Sp4 = (float4*)Sp;
#pragma unroll
        for (int j = 0; j < 4; ++j)
            Sp4[j] = make_float4(z[4*j], z[4*j+1], z[4*j+2], z[4*j+3]);
        return;
    }

    // ---- emit role: chunk 0, z from x0 (z = x0 / B_tilde, guarded) ----
    float cbt[16];
    {
        const float* Bp = B + d * NS + n0;
        const float* Cp = Cm + d * NS + n0;
        const float* Xp = x0 + d * NS + n0;
#pragma unroll
        for (int k = 0; k < 16; ++k) {
            float bt = (1.0f - a[k]) * Bp[k] / Ap[k];
            cbt[k] = Cp[k] * bt;               // C * B_tilde
            float x0v = Xp[k];
            z[k] = (x0v == 0.0f) ? 0.0f : ((bt != 0.0f) ? (x0v / bt) : 0.0f);
        }
    }
    float* yptr = y + (size_t)b * SEQ * DM + d;  // chunk 0 -> t0 = 0
    float4 rC = *(const float4*)gsrc;
    float4 rD = *(const float4*)(gsrc + half);
    *(float4*)slotA = rC;
    *(float4*)(slotA + 256) = rD;
    rC = *(const float4*)(gsrc + tadv);
    rD = *(const float4*)(gsrc + tadv + half);
    gsrc += 2 * tadv;
    for (int t = 0; t < ntiles; ++t) {
        if (t + 1 < ntiles) {
            float* wp = slotA + (((t + 1) & 1) << 9);
            *(float4*)wp = rC;
            *(float4*)(wp + 256) = rD;
        }
        if (t + 2 < ntiles) {
            rC = *(const float4*)gsrc;
            rD = *(const float4*)(gsrc + half);
            gsrc += tadv;
        }
        const float* tb = &tiles[wid][t & 1][0][0] + c;
#pragma unroll
        for (int s = 0; s < TSTEP; ++s) {
            float uv = tb[s << 4];
            float p0 = 0.0f, p1 = 0.0f;
#pragma unroll
            for (int k = 0; k < 16; k += 2) {
                z[k]   = fmaf(a[k],   z[k],   uv); p0 = fmaf(cbt[k],   z[k],   p0);
                z[k+1] = fmaf(a[k+1], z[k+1], uv); p1 = fmaf(cbt[k+1], z[k+1], p1);
            }
            float p = p0 + p1;
            p += __shfl_xor(p, 1);   // combine the four quarter-state partials
            p += __shfl_xor(p, 2);
            if (sub == 0) yptr[s * DM] = p;
        }
        yptr += tadv;
    }
}

// ---------------- pass2: chunk-carry prefix (r7-proven) ----------------
__global__ void pass2_kernel(float* __restrict__ S,
                             const float* __restrict__ log_dt,
                             const float* __restrict__ A_real,
                             const float* __restrict__ B,
                             const float* __restrict__ x0,
                             int C, int Tc) {
    int idx = blockIdx.x * blockDim.x + threadIdx.x;  // b*16384 + d*64 + n
    if (idx >= BATCH * DM * NS) return;
    int dn = idx & (DM * NS - 1);
    int d = dn >> 6;
    float ar = A_real[dn];
    float dt = expf(log_dt[d]);
    float aT = expf(ar * dt * (float)Tc);  // a^Tc
    float x0v = x0[dn];
    float prev;
    if (x0v == 0.0f) {
        prev = 0.0f;                       // common/bench case
    } else {
        float at = expf(ar * dt);
        float bt = (1.0f - at) * B[dn] / ar;
        prev = (bt != 0.0f) ? (x0v / bt) : 0.0f;
    }
    const size_t stride = (size_t)BATCH * DM * NS;
    if (C == 16) {
        float v[15];
#pragma unroll
        for (int g = 0; g < 15; ++g) v[g] = S[(size_t)g * stride + idx];
#pragma unroll
        for (int g = 0; g < 15; ++g) {
            S[(size_t)g * stride + idx] = prev;
            prev = fmaf(aT, prev, v[g]);
        }
        S[15 * stride + idx] = prev;
    } else {
        for (int g = 0; g < C - 1; ++g) {
            float* p = S + (size_t)g * stride + idx;
            float s = *p;
            *p = prev;
            prev = fmaf(aT, prev, s);
        }
        S[(size_t)(C - 1) * stride + idx] = prev;
    }
}

// ---------------- pass3: emit chunks 1..C-1 from S[g] ----------------
__global__ __launch_bounds__(256, 2)
void pass3_kernel(const float* __restrict__ u,
                  const float* __restrict__ log_dt,
                  const float* __restrict__ A_real,
                  const float* __restrict__ B,
                  const float* __restrict__ Cm,
                  const float* __restrict__ S,
                  float* __restrict__ y, int Tc) {
    __shared__ float tiles[4][2][TSTEP][16];
    int wid  = threadIdx.x >> 6;
    int lane = threadIdx.x & 63;
    int wave = (blockIdx.x << 2) | wid;
    int g  = 1 + (wave >> 9);          // chunks 1..C-1
    int w  = wave & 511;
    int b  = w >> 4;
    int d0 = (w & 15) << 4;
    int c   = lane >> 2;
    int sub = lane & 3;
    int d   = d0 + c;
    int n0  = sub << 4;

    float dt = expf(log_dt[d]);
    const float* Ap = A_real + d * NS + n0;
    float a[16], cbt[16], z[16];
    {
        const float* Bp = B + d * NS + n0;
        const float* Cp = Cm + d * NS + n0;
#pragma unroll
        for (int k = 0; k < 16; ++k) {
            float at = expf(Ap[k] * dt);
            a[k] = at;
            cbt[k] = Cp[k] * ((1.0f - at) * Bp[k] / Ap[k]);  // C * B_tilde
        }
        const float4* Sp4 = (const float4*)(S +
            (((size_t)g * BATCH + b) * DM + d) * NS + n0);
#pragma unroll
        for (int j = 0; j < 4; ++j) {
            float4 v = Sp4[j];
            z[4*j] = v.x; z[4*j+1] = v.y; z[4*j+2] = v.z; z[4*j+3] = v.w;
        }
    }

    const size_t tadv = (size_t)TSTEP * DM;
    const size_t half = (size_t)16 * DM;
    float* slotA = &tiles[wid][0][0][0] + (lane << 2);
    const int ntiles = Tc / TSTEP;
    const float* gsrc = u + (size_t)b * SEQ * DM + (size_t)(g * Tc) * DM
                        + (size_t)(lane >> 2) * DM + d0 + ((lane & 3) << 2);
    float* yptr = y + (size_t)b * SEQ * DM + (size_t)(g * Tc) * DM + d;

    float4 rC = *(const float4*)gsrc;
    float4 rD = *(const float4*)(gsrc + half);
    *(float4*)slotA = rC;
    *(float4*)(slotA + 256) = rD;
    rC = *(const float4*)(gsrc + tadv);
    rD = *(const float4*)(gsrc + tadv + half);
    gsrc += 2 * tadv;

    for (int t = 0; t < ntiles; ++t) {
        if (t + 1 < ntiles) {
            float* wp = slotA + (((t + 1) & 1) << 9);
            *(float4*)wp = rC;
            *(float4*)(wp + 256) = rD;
        }
        if (t + 2 < ntiles) {
            rC = *(const float4*)gsrc;
            rD = *(const float4*)(gsrc + half);
            gsrc += tadv;
        }
        const float* tb = &tiles[wid][t & 1][0][0] + c;
#pragma unroll
        for (int s = 0; s < TSTEP; ++s) {
            float uv = tb[s << 4];              // broadcast ds_read_b32
            float p0 = 0.0f, p1 = 0.0f;
#pragma unroll
            for (int k = 0; k < 16; k += 2) {
                z[k]   = fmaf(a[k],   z[k],   uv); p0 = fmaf(cbt[k],   z[k],   p0);
                z[k+1] = fmaf(a[k+1], z[k+1], uv); p1 = fmaf(cbt[k+1], z[k+1], p1);
            }
            float p = p0 + p1;
            p += __shfl_xor(p, 1);
            p += __shfl_xor(p, 2);
            if (sub == 0) yptr[s * DM] = p;
        }
        yptr += tadv;
    }
}

extern "C" void kernel_launch(void* const* d_in, const int* in_sizes, int n_in,
                              void* d_out, int out_size, void* d_ws, size_t ws_size,
                              hipStream_t stream) {
    const float* u      = (const float*)d_in[0];
    const float* log_dt = (const float*)d_in[1];
    const float* A_real = (const float*)d_in[2];
    const float* B      = (const float*)d_in[3];
    const float* Cm     = (const float*)d_in[4];
    const float* x0     = (const float*)d_in[5];
    float* y = (float*)d_out;
    float* S = (float*)d_ws;

    const size_t per_chunk = (size_t)BATCH * DM * NS * sizeof(float);  // 2 MB
    int C = 16;  // needs C slots in ws (pass2 writes z_in for all chunks)
    while (C > 1 && (size_t)C * per_chunk > ws_size) C >>= 1;
    if ((size_t)C * per_chunk > ws_size) C = 1;
    int Tc = SEQ / C;

    // passA: 128 emit blocks (chunk 0) first, then (C-1)*128 pass1 blocks
    passA_kernel<<<dim3(C * 128), dim3(256), 0, stream>>>(
        u, log_dt, A_real, B, Cm, S, x0, y, Tc);
    if (C > 1) {
        pass2_kernel<<<dim3((BATCH * DM * NS) / 256), dim3(256), 0, stream>>>(
            S, log_dt, A_real, B, x0, C, Tc);
        pass3_kernel<<<dim3((C - 1) * 128), dim3(256), 0, stream>>>(
            u, log_dt, A_real, B, Cm, S, y, Tc);
    }
}